// Round 2
// baseline (334.832 us; speedup 1.0000x reference)
//
#include <hip/hip_runtime.h>

#define NH 8
#define HD 32
#define SUMP 16
#define LQ 4096
#define BS 4
#define LV 8500
#define NQ (BS * LQ)   // 16384
#define MV (BS * LV)   // 34000

typedef short s16x8 __attribute__((ext_vector_type(8)));
typedef float f32x4 __attribute__((ext_vector_type(4)));

__device__ __forceinline__ float bf2f(unsigned short u) {
    union { unsigned int i; float f; } x; x.i = ((unsigned int)u) << 16; return x.f;
}
__device__ __forceinline__ unsigned short f2bf(float f) {
    union { float f; unsigned int i; } x; x.f = f;
    unsigned int r = x.i + 0x7fffu + ((x.i >> 16) & 1u);
    return (unsigned short)(r >> 16);
}
// split fp32 -> bf16 hi + bf16 lo (a ~= hi + lo, error ~2^-17 |a|)
__device__ __forceinline__ void split8(const float* f, s16x8& hi, s16x8& lo) {
    #pragma unroll
    for (int i = 0; i < 8; ++i) {
        unsigned short h = f2bf(f[i]);
        float r = f[i] - bf2f(h);
        hi[i] = (short)h;
        lo[i] = (short)f2bf(r);
    }
}

// ---------- prep: transpose + split weights into Wt_hi/Wt_lo [N][K], concat biases ----------
__global__ __launch_bounds__(256) void prep_kernel(
    const float* __restrict__ Wv, const float* __restrict__ Woff,
    const float* __restrict__ Wattn, const float* __restrict__ Wo,
    const float* __restrict__ boff, const float* __restrict__ battn,
    unsigned short* __restrict__ WtVh, unsigned short* __restrict__ WtVl,
    unsigned short* __restrict__ WtOAh, unsigned short* __restrict__ WtOAl,
    unsigned short* __restrict__ WtOh, unsigned short* __restrict__ WtOl,
    float* __restrict__ biasOA)
{
    int r = blockIdx.x;      // 0..895
    int k = threadIdx.x;     // 0..255
    float w; unsigned short* ph; unsigned short* pl; size_t idx;
    if (r < 256)      { w = Wv[k * 256 + r];                 ph = WtVh;  pl = WtVl;  idx = (size_t)r * 256 + k; }
    else if (r < 512) { int n = r - 256; w = Woff[k * 256 + n];  ph = WtOAh; pl = WtOAl; idx = (size_t)n * 256 + k; }
    else if (r < 640) { int n = r - 512; w = Wattn[k * 128 + n]; ph = WtOAh; pl = WtOAl; idx = (size_t)(256 + n) * 256 + k; }
    else              { int n = r - 640; w = Wo[k * 256 + n];    ph = WtOh;  pl = WtOl;  idx = (size_t)n * 256 + k; }
    unsigned short h = f2bf(w);
    float res = w - bf2f(h);
    ph[idx] = h;
    pl[idx] = f2bf(res);
    if (r == 0) biasOA[k] = boff[k];
    if (r == 1 && k < 128) biasOA[256 + k] = battn[k];
}

// ---------- split-bf16 MFMA GEMM: C[M][N] = A[M][K] @ Bt[N][K]^T + bias (near-fp32 accurate) ----------
#define TM 128
#define TN 64
#define BK 32
#define LDT 40   // padded LDS row stride (elements); 80B rows, 16B aligned

__global__ __launch_bounds__(256) void gemm_bias_kernel(
    const float* __restrict__ A,
    const unsigned short* __restrict__ Bth,
    const unsigned short* __restrict__ Btl,
    const float* __restrict__ bias,
    float* __restrict__ C,
    int M, int N, int K)
{
    __shared__ __align__(16) unsigned short Ah[TM * LDT];
    __shared__ __align__(16) unsigned short Al[TM * LDT];
    __shared__ __align__(16) unsigned short Bh[TN * LDT];
    __shared__ __align__(16) unsigned short Bl[TN * LDT];
    const int t = threadIdx.x;
    const int wave = t >> 6, lane = t & 63;
    const int quad = lane >> 4, l16 = lane & 15;
    const int m0 = blockIdx.x * TM;
    const int n0 = blockIdx.y * TN;

    f32x4 acc[2][4] = {};

    for (int k0 = 0; k0 < K; k0 += BK) {
        // stage A tile 128x32: load fp32, split to hi/lo bf16
        #pragma unroll
        for (int c = 0; c < 2; ++c) {
            int row = (t >> 2) + c * 64;
            int kq = t & 3;
            int gm = m0 + row;
            float buf[8] = {};
            if (gm < M) {
                *(float4*)(buf + 0) = *(const float4*)(A + (size_t)gm * K + k0 + kq * 8);
                *(float4*)(buf + 4) = *(const float4*)(A + (size_t)gm * K + k0 + kq * 8 + 4);
            }
            s16x8 hi, lo;
            split8(buf, hi, lo);
            *(s16x8*)(Ah + row * LDT + kq * 8) = hi;
            *(s16x8*)(Al + row * LDT + kq * 8) = lo;
        }
        // stage B tile 64x32 (pre-split)
        {
            int nrow = t >> 2;
            int kq = t & 3;
            size_t g = (size_t)(n0 + nrow) * K + k0 + kq * 8;
            *(s16x8*)(Bh + nrow * LDT + kq * 8) = *(const s16x8*)(Bth + g);
            *(s16x8*)(Bl + nrow * LDT + kq * 8) = *(const s16x8*)(Btl + g);
        }
        __syncthreads();

        s16x8 afh[2], afl[2], bfh[4], bfl[4];
        #pragma unroll
        for (int mi = 0; mi < 2; ++mi) {
            int r = (wave * 32 + mi * 16 + l16) * LDT + quad * 8;
            afh[mi] = *(const s16x8*)(Ah + r);
            afl[mi] = *(const s16x8*)(Al + r);
        }
        #pragma unroll
        for (int ni = 0; ni < 4; ++ni) {
            int r = (ni * 16 + l16) * LDT + quad * 8;
            bfh[ni] = *(const s16x8*)(Bh + r);
            bfl[ni] = *(const s16x8*)(Bl + r);
        }
        #pragma unroll
        for (int mi = 0; mi < 2; ++mi) {
            #pragma unroll
            for (int ni = 0; ni < 4; ++ni) {
                acc[mi][ni] = __builtin_amdgcn_mfma_f32_16x16x32_bf16(afh[mi], bfh[ni], acc[mi][ni], 0, 0, 0);
                acc[mi][ni] = __builtin_amdgcn_mfma_f32_16x16x32_bf16(afh[mi], bfl[ni], acc[mi][ni], 0, 0, 0);
                acc[mi][ni] = __builtin_amdgcn_mfma_f32_16x16x32_bf16(afl[mi], bfh[ni], acc[mi][ni], 0, 0, 0);
            }
        }
        __syncthreads();
    }

    // epilogue: C/D layout col=lane&15, row=quad*4+reg (m89-verified)
    #pragma unroll
    for (int ni = 0; ni < 4; ++ni) {
        int n = n0 + ni * 16 + l16;
        float bv = bias[n];
        #pragma unroll
        for (int mi = 0; mi < 2; ++mi) {
            int mb = m0 + wave * 32 + mi * 16 + quad * 4;
            #pragma unroll
            for (int r = 0; r < 4; ++r) {
                int m = mb + r;
                if (m < M) C[(size_t)m * N + n] = acc[mi][ni][r] + bv;
            }
        }
    }
}

// ---------- sampling: softmax + bilinear gather + weighted sum (all fp32) ----------
__global__ __launch_bounds__(256) void sample_kernel(
    const float* __restrict__ v,             // [MV][256] fp32, col = h*32+d
    const float* __restrict__ oa,            // [NQ][384] fp32: 0..255 offsets, 256..383 logits
    const float* __restrict__ refp,          // [NQ][4] fp32
    float* __restrict__ mid)                 // [NQ][256] fp32
{
    const int row = blockIdx.x;      // b*LQ + q
    const int b = row >> 12;         // LQ = 4096
    const int t = threadIdx.x;

    __shared__ float s_lx[NH][SUMP];
    __shared__ float s_ly[NH][SUMP];
    __shared__ float s_w[NH][SUMP];
    __shared__ float s_mx[NH], s_is[NH];

    const float4 r4 = *(const float4*)(refp + (size_t)row * 4);
    const float rx = r4.x, ry = r4.y, rw = r4.z, rh = r4.w;

    if (t < 128) {                   // t = h*16 + p
        int h = t >> 4, p = t & 15;
        float ox = oa[(size_t)row * 384 + t * 2 + 0];
        float oy = oa[(size_t)row * 384 + t * 2 + 1];
        // loc = ref_xy + off * (1/P) * ref_wh * OFFSET_SCALE = ref_xy + off*0.125*ref_wh
        s_lx[h][p] = rx + ox * 0.125f * rw;
        s_ly[h][p] = ry + oy * 0.125f * rh;
        s_w[h][p] = oa[(size_t)row * 384 + 256 + t];
    }
    __syncthreads();
    if (t < NH) {
        float mx = -1e30f;
        #pragma unroll
        for (int p = 0; p < SUMP; ++p) mx = fmaxf(mx, s_w[t][p]);
        float sm = 0.f;
        #pragma unroll
        for (int p = 0; p < SUMP; ++p) sm += __expf(s_w[t][p] - mx);
        s_mx[t] = mx; s_is[t] = 1.f / sm;
    }
    __syncthreads();
    if (t < 128) {
        int h = t >> 4, p = t & 15;
        s_w[h][p] = __expf(s_w[h][p] - s_mx[h]) * s_is[h];
    }
    __syncthreads();

    const int h = t >> 5, d = t & 31;
    const float* vb = v + (size_t)b * (LV * 256) + h * 32 + d;
    float acc = 0.f;
    const int dims[4] = {80, 40, 20, 10};
    const int vst[4] = {0, 6400, 8000, 8400};
    #pragma unroll
    for (int l = 0; l < 4; ++l) {
        const int Wl = dims[l];   // Hl == Wl at every level
        const float* vl = vb + (size_t)vst[l] * 256;
        #pragma unroll
        for (int pp = 0; pp < 4; ++pp) {
            int p = l * 4 + pp;
            float w = s_w[h][p];
            float x = s_lx[h][p] * Wl - 0.5f;
            float y = s_ly[h][p] * Wl - 0.5f;
            float x0f = floorf(x), y0f = floorf(y);
            float lx = x - x0f, ly = y - y0f;
            int x0 = (int)x0f, y0 = (int)y0f;
            int x1 = x0 + 1, y1 = y0 + 1;
            bool vx0 = (x0 >= 0) && (x0 < Wl), vx1 = (x1 >= 0) && (x1 < Wl);
            bool vy0 = (y0 >= 0) && (y0 < Wl), vy1 = (y1 >= 0) && (y1 < Wl);
            if (vy0) {
                if (vx0) acc += w * (1.f - lx) * (1.f - ly) * vl[(size_t)(y0 * Wl + x0) * 256];
                if (vx1) acc += w * lx * (1.f - ly) * vl[(size_t)(y0 * Wl + x1) * 256];
            }
            if (vy1) {
                if (vx0) acc += w * (1.f - lx) * ly * vl[(size_t)(y1 * Wl + x0) * 256];
                if (vx1) acc += w * lx * ly * vl[(size_t)(y1 * Wl + x1) * 256];
            }
        }
    }
    mid[(size_t)row * 256 + t] = acc;
}

extern "C" void kernel_launch(void* const* d_in, const int* in_sizes, int n_in,
                              void* d_out, int out_size, void* d_ws, size_t ws_size,
                              hipStream_t stream) {
    const float* query  = (const float*)d_in[0];   // [4,4096,256]
    const float* refp   = (const float*)d_in[1];   // [4,4096,1,4]
    const float* value  = (const float*)d_in[2];   // [4,8500,256]
    const float* W_off  = (const float*)d_in[3];   // [256,256]
    const float* b_off  = (const float*)d_in[4];   // [256]
    const float* W_attn = (const float*)d_in[5];   // [256,128]
    const float* b_attn = (const float*)d_in[6];   // [128]
    const float* W_v    = (const float*)d_in[7];   // [256,256]
    const float* b_v    = (const float*)d_in[8];   // [256]
    const float* W_o    = (const float*)d_in[9];   // [256,256]
    const float* b_o    = (const float*)d_in[10];  // [256]

    char* ws = (char*)d_ws;
    float*          v_f32  = (float*)(ws + 0);                  // 34,816,000 B
    float*          oa_f32 = (float*)(ws + 34816000);           // 25,165,824 B
    float*          mid    = (float*)(ws + 59981824);           // 16,777,216 B
    unsigned short* WtVh   = (unsigned short*)(ws + 76759040);  //    131,072 B
    unsigned short* WtVl   = (unsigned short*)(ws + 76890112);  //    131,072 B
    unsigned short* WtOAh  = (unsigned short*)(ws + 77021184);  //    196,608 B
    unsigned short* WtOAl  = (unsigned short*)(ws + 77217792);  //    196,608 B
    unsigned short* WtOh   = (unsigned short*)(ws + 77414400);  //    131,072 B
    unsigned short* WtOl   = (unsigned short*)(ws + 77545472);  //    131,072 B
    float*          biasOA = (float*)(ws + 77676544);           //      1,536 B

    prep_kernel<<<896, 256, 0, stream>>>(W_v, W_off, W_attn, W_o, b_off, b_attn,
                                         WtVh, WtVl, WtOAh, WtOAl, WtOh, WtOl, biasOA);
    // v = value @ W_v + b_v
    gemm_bias_kernel<<<dim3((MV + TM - 1) / TM, 256 / TN), 256, 0, stream>>>(
        value, WtVh, WtVl, b_v, v_f32, MV, 256, 256);
    // off|attn = query @ [W_off|W_attn] + bias
    gemm_bias_kernel<<<dim3(NQ / TM, 384 / TN), 256, 0, stream>>>(
        query, WtOAh, WtOAl, biasOA, oa_f32, NQ, 384, 256);
    // softmax + bilinear sampling -> mid (fp32)
    sample_kernel<<<NQ, 256, 0, stream>>>(v_f32, oa_f32, refp, mid);
    // out = mid @ W_o + b_o  (fp32 out)
    gemm_bias_kernel<<<dim3(NQ / TM, 256 / TN), 256, 0, stream>>>(
        mid, WtOh, WtOl, b_o, (float*)d_out, NQ, 256, 256);
}

// Round 3
// 263.986 us; speedup vs baseline: 1.2684x; 1.2684x over previous
//
#include <hip/hip_runtime.h>

#define NH 8
#define HD 32
#define SUMP 16
#define LQ 4096
#define BS 4
#define LV 8500
#define NQ (BS * LQ)   // 16384
#define MV (BS * LV)   // 34000

typedef short s16x8 __attribute__((ext_vector_type(8)));
typedef float f32x4 __attribute__((ext_vector_type(4)));

__device__ __forceinline__ float bf2f(unsigned short u) {
    union { unsigned int i; float f; } x; x.i = ((unsigned int)u) << 16; return x.f;
}
__device__ __forceinline__ unsigned short f2bf(float f) {
    union { float f; unsigned int i; } x; x.f = f;
    unsigned int r = x.i + 0x7fffu + ((x.i >> 16) & 1u);
    return (unsigned short)(r >> 16);
}
// split fp32 -> bf16 hi + bf16 lo (a ~= hi + lo, error ~2^-17 |a|)
__device__ __forceinline__ void split8(const float* f, s16x8& hi, s16x8& lo) {
    #pragma unroll
    for (int i = 0; i < 8; ++i) {
        unsigned short h = f2bf(f[i]);
        float r = f[i] - bf2f(h);
        hi[i] = (short)h;
        lo[i] = (short)f2bf(r);
    }
}

// ---------- prep: transpose + split weights into Wt_hi/Wt_lo [N][K], concat biases ----------
__global__ __launch_bounds__(256) void prep_kernel(
    const float* __restrict__ Wv, const float* __restrict__ Woff,
    const float* __restrict__ Wattn, const float* __restrict__ Wo,
    const float* __restrict__ boff, const float* __restrict__ battn,
    unsigned short* __restrict__ WtVh, unsigned short* __restrict__ WtVl,
    unsigned short* __restrict__ WtOAh, unsigned short* __restrict__ WtOAl,
    unsigned short* __restrict__ WtOh, unsigned short* __restrict__ WtOl,
    float* __restrict__ biasOA)
{
    int r = blockIdx.x;      // 0..895
    int k = threadIdx.x;     // 0..255
    float w; unsigned short* ph; unsigned short* pl; size_t idx;
    if (r < 256)      { w = Wv[k * 256 + r];                 ph = WtVh;  pl = WtVl;  idx = (size_t)r * 256 + k; }
    else if (r < 512) { int n = r - 256; w = Woff[k * 256 + n];  ph = WtOAh; pl = WtOAl; idx = (size_t)n * 256 + k; }
    else if (r < 640) { int n = r - 512; w = Wattn[k * 128 + n]; ph = WtOAh; pl = WtOAl; idx = (size_t)(256 + n) * 256 + k; }
    else              { int n = r - 640; w = Wo[k * 256 + n];    ph = WtOh;  pl = WtOl;  idx = (size_t)n * 256 + k; }
    unsigned short h = f2bf(w);
    float res = w - bf2f(h);
    ph[idx] = h;
    pl[idx] = f2bf(res);
    if (r == 0) biasOA[k] = boff[k];
    if (r == 1 && k < 128) biasOA[256 + k] = battn[k];
}

// ---------- split-bf16 MFMA GEMM: C[M][N] = A[M][K] @ Bt[N][K]^T + bias ----------
#define TM 128
#define TN 128
#define BK 32
#define LDT 40   // padded LDS row stride (elements); 80B rows, 16B aligned

__global__ __launch_bounds__(256) void gemm_bias_kernel(
    const float* __restrict__ A,
    const unsigned short* __restrict__ Bth,
    const unsigned short* __restrict__ Btl,
    const float* __restrict__ bias,
    float* __restrict__ C,
    int M, int N, int K)
{
    __shared__ __align__(16) unsigned short Ah[TM * LDT];
    __shared__ __align__(16) unsigned short Al[TM * LDT];
    __shared__ __align__(16) unsigned short Bh[TN * LDT];
    __shared__ __align__(16) unsigned short Bl[TN * LDT];
    const int t = threadIdx.x;
    const int wave = t >> 6, lane = t & 63;
    const int quad = lane >> 4, l16 = lane & 15;
    const int m0 = blockIdx.x * TM;
    const int n0 = blockIdx.y * TN;

    f32x4 acc[2][8] = {};

    for (int k0 = 0; k0 < K; k0 += BK) {
        // stage A tile 128x32: load fp32, split to hi/lo bf16
        #pragma unroll
        for (int c = 0; c < 2; ++c) {
            int row = (t >> 2) + c * 64;
            int kq = t & 3;
            int gm = m0 + row;
            float buf[8] = {};
            if (gm < M) {
                *(float4*)(buf + 0) = *(const float4*)(A + (size_t)gm * K + k0 + kq * 8);
                *(float4*)(buf + 4) = *(const float4*)(A + (size_t)gm * K + k0 + kq * 8 + 4);
            }
            s16x8 hi, lo;
            split8(buf, hi, lo);
            *(s16x8*)(Ah + row * LDT + kq * 8) = hi;
            *(s16x8*)(Al + row * LDT + kq * 8) = lo;
        }
        // stage B tile 128x32 (pre-split bf16 hi/lo)
        #pragma unroll
        for (int c = 0; c < 2; ++c) {
            int row = (t >> 2) + c * 64;
            int kq = t & 3;
            size_t g = (size_t)(n0 + row) * K + k0 + kq * 8;
            *(s16x8*)(Bh + row * LDT + kq * 8) = *(const s16x8*)(Bth + g);
            *(s16x8*)(Bl + row * LDT + kq * 8) = *(const s16x8*)(Btl + g);
        }
        __syncthreads();

        s16x8 afh[2], afl[2], bfh[8], bfl[8];
        #pragma unroll
        for (int mi = 0; mi < 2; ++mi) {
            int r = (wave * 32 + mi * 16 + l16) * LDT + quad * 8;
            afh[mi] = *(const s16x8*)(Ah + r);
            afl[mi] = *(const s16x8*)(Al + r);
        }
        #pragma unroll
        for (int ni = 0; ni < 8; ++ni) {
            int r = (ni * 16 + l16) * LDT + quad * 8;
            bfh[ni] = *(const s16x8*)(Bh + r);
            bfl[ni] = *(const s16x8*)(Bl + r);
        }
        #pragma unroll
        for (int mi = 0; mi < 2; ++mi) {
            #pragma unroll
            for (int ni = 0; ni < 8; ++ni) {
                acc[mi][ni] = __builtin_amdgcn_mfma_f32_16x16x32_bf16(afh[mi], bfh[ni], acc[mi][ni], 0, 0, 0);
                acc[mi][ni] = __builtin_amdgcn_mfma_f32_16x16x32_bf16(afh[mi], bfl[ni], acc[mi][ni], 0, 0, 0);
                acc[mi][ni] = __builtin_amdgcn_mfma_f32_16x16x32_bf16(afl[mi], bfh[ni], acc[mi][ni], 0, 0, 0);
            }
        }
        __syncthreads();
    }

    // epilogue: C/D layout col=lane&15, row=quad*4+reg (m89-verified)
    #pragma unroll
    for (int ni = 0; ni < 8; ++ni) {
        int n = n0 + ni * 16 + l16;
        float bv = bias[n];
        #pragma unroll
        for (int mi = 0; mi < 2; ++mi) {
            int mb = m0 + wave * 32 + mi * 16 + quad * 4;
            #pragma unroll
            for (int r = 0; r < 4; ++r) {
                int m = mb + r;
                if (m < M) C[(size_t)m * N + n] = acc[mi][ni][r] + bv;
            }
        }
    }
}

// ---------- sampling: softmax + bilinear gather + weighted sum (branchless, float4) ----------
#define QPB 4   // queries per block

__global__ __launch_bounds__(256) void sample_kernel(
    const float* __restrict__ v,             // [MV][256] fp32, col = h*32+d
    const float* __restrict__ oa,            // [NQ][384] fp32: 0..255 offsets, 256..383 logits
    const float* __restrict__ refp,          // [NQ][4] fp32
    float* __restrict__ mid)                 // [NQ][256] fp32
{
    const int row0 = blockIdx.x * QPB;
    const int t = threadIdx.x;

    __shared__ float s_lx[QPB][NH * SUMP];
    __shared__ float s_ly[QPB][NH * SUMP];
    __shared__ float s_w[QPB][NH * SUMP];
    __shared__ float s_mx[QPB][NH], s_is[QPB][NH];

    // --- location + logit prep: 4*128 = 512 entries, 2 per thread ---
    #pragma unroll
    for (int i = t; i < QPB * 128; i += 256) {
        int q = i >> 7, e = i & 127;          // e = h*16 + p
        int row = row0 + q;
        float4 r4 = *(const float4*)(refp + (size_t)row * 4);
        float2 o2 = *(const float2*)(oa + (size_t)row * 384 + e * 2);
        // loc = ref_xy + off * (1/P) * ref_wh * OFFSET_SCALE = ref_xy + off*0.125*ref_wh
        s_lx[q][e] = r4.x + o2.x * 0.125f * r4.z;
        s_ly[q][e] = r4.y + o2.y * 0.125f * r4.w;
        s_w[q][e] = oa[(size_t)row * 384 + 256 + e];
    }
    __syncthreads();
    if (t < QPB * NH) {                        // 32 threads: one (q,h) each
        int q = t >> 3, h = t & 7;
        float mx = -1e30f;
        #pragma unroll
        for (int p = 0; p < SUMP; ++p) mx = fmaxf(mx, s_w[q][h * 16 + p]);
        float sm = 0.f;
        #pragma unroll
        for (int p = 0; p < SUMP; ++p) sm += __expf(s_w[q][h * 16 + p] - mx);
        s_mx[q][h] = mx; s_is[q][h] = 1.f / sm;
    }
    __syncthreads();
    #pragma unroll
    for (int i = t; i < QPB * 128; i += 256) {
        int q = i >> 7, e = i & 127, h = e >> 4;
        s_w[q][e] = __expf(s_w[q][e] - s_mx[q][h]) * s_is[q][h];
    }
    __syncthreads();

    // --- gather: q = t>>6; within query: h = (t>>3)&7, dv = t&7 (float4 over HD) ---
    const int q = t >> 6;
    const int h = (t >> 3) & 7;
    const int dv = t & 7;
    const int row = row0 + q;
    const int b = row >> 12;                  // LQ = 4096
    // float4-unit base: element index (b*LV + idx)*256 + h*32 + dv*4  ->  /4
    const float4* vb4 = (const float4*)v + (size_t)b * LV * 64 + h * 8 + dv;

    f32x4 acc = {};
    const int dims[4] = {80, 40, 20, 10};
    const int vst[4] = {0, 6400, 8000, 8400};
    #pragma unroll
    for (int l = 0; l < 4; ++l) {
        const int Wl = dims[l];               // Hl == Wl at every level
        const float4* vl4 = vb4 + (size_t)vst[l] * 64;
        #pragma unroll
        for (int pp = 0; pp < 4; ++pp) {
            int e = h * 16 + l * 4 + pp;
            float w = s_w[q][e];
            float x = s_lx[q][e] * Wl - 0.5f;
            float y = s_ly[q][e] * Wl - 0.5f;
            float x0f = floorf(x), y0f = floorf(y);
            float lx = x - x0f, ly = y - y0f;
            int x0 = (int)x0f, y0 = (int)y0f;
            int x1 = x0 + 1, y1 = y0 + 1;
            // branchless: clamp index (always-legal load), fold validity into weight
            float mx0 = (x0 >= 0 && x0 < Wl) ? 1.f : 0.f;
            float mx1 = (x1 >= 0 && x1 < Wl) ? 1.f : 0.f;
            float my0 = (y0 >= 0 && y0 < Wl) ? 1.f : 0.f;
            float my1 = (y1 >= 0 && y1 < Wl) ? 1.f : 0.f;
            int cx0 = min(max(x0, 0), Wl - 1), cx1 = min(max(x1, 0), Wl - 1);
            int cy0 = min(max(y0, 0), Wl - 1), cy1 = min(max(y1, 0), Wl - 1);
            float4 g00 = vl4[(size_t)(cy0 * Wl + cx0) * 64];
            float4 g01 = vl4[(size_t)(cy0 * Wl + cx1) * 64];
            float4 g10 = vl4[(size_t)(cy1 * Wl + cx0) * 64];
            float4 g11 = vl4[(size_t)(cy1 * Wl + cx1) * 64];
            float w00 = w * (1.f - lx) * (1.f - ly) * mx0 * my0;
            float w01 = w * lx * (1.f - ly) * mx1 * my0;
            float w10 = w * (1.f - lx) * ly * mx0 * my1;
            float w11 = w * lx * ly * mx1 * my1;
            acc[0] += w00 * g00.x + w01 * g01.x + w10 * g10.x + w11 * g11.x;
            acc[1] += w00 * g00.y + w01 * g01.y + w10 * g10.y + w11 * g11.y;
            acc[2] += w00 * g00.z + w01 * g01.z + w10 * g10.z + w11 * g11.z;
            acc[3] += w00 * g00.w + w01 * g01.w + w10 * g10.w + w11 * g11.w;
        }
    }
    *(f32x4*)(mid + (size_t)row * 256 + h * 32 + dv * 4) = acc;
}

extern "C" void kernel_launch(void* const* d_in, const int* in_sizes, int n_in,
                              void* d_out, int out_size, void* d_ws, size_t ws_size,
                              hipStream_t stream) {
    const float* query  = (const float*)d_in[0];   // [4,4096,256]
    const float* refp   = (const float*)d_in[1];   // [4,4096,1,4]
    const float* value  = (const float*)d_in[2];   // [4,8500,256]
    const float* W_off  = (const float*)d_in[3];   // [256,256]
    const float* b_off  = (const float*)d_in[4];   // [256]
    const float* W_attn = (const float*)d_in[5];   // [256,128]
    const float* b_attn = (const float*)d_in[6];   // [128]
    const float* W_v    = (const float*)d_in[7];   // [256,256]
    const float* b_v    = (const float*)d_in[8];   // [256]
    const float* W_o    = (const float*)d_in[9];   // [256,256]
    const float* b_o    = (const float*)d_in[10];  // [256]

    char* ws = (char*)d_ws;
    float*          v_f32  = (float*)(ws + 0);                  // 34,816,000 B
    float*          oa_f32 = (float*)(ws + 34816000);           // 25,165,824 B
    float*          mid    = (float*)(ws + 59981824);           // 16,777,216 B
    unsigned short* WtVh   = (unsigned short*)(ws + 76759040);  //    131,072 B
    unsigned short* WtVl   = (unsigned short*)(ws + 76890112);  //    131,072 B
    unsigned short* WtOAh  = (unsigned short*)(ws + 77021184);  //    196,608 B
    unsigned short* WtOAl  = (unsigned short*)(ws + 77217792);  //    196,608 B
    unsigned short* WtOh   = (unsigned short*)(ws + 77414400);  //    131,072 B
    unsigned short* WtOl   = (unsigned short*)(ws + 77545472);  //    131,072 B
    float*          biasOA = (float*)(ws + 77676544);           //      1,536 B

    prep_kernel<<<896, 256, 0, stream>>>(W_v, W_off, W_attn, W_o, b_off, b_attn,
                                         WtVh, WtVl, WtOAh, WtOAl, WtOh, WtOl, biasOA);
    // v = value @ W_v + b_v
    gemm_bias_kernel<<<dim3((MV + TM - 1) / TM, 256 / TN), 256, 0, stream>>>(
        value, WtVh, WtVl, b_v, v_f32, MV, 256, 256);
    // off|attn = query @ [W_off|W_attn] + bias
    gemm_bias_kernel<<<dim3(NQ / TM, 384 / TN), 256, 0, stream>>>(
        query, WtOAh, WtOAl, biasOA, oa_f32, NQ, 384, 256);
    // softmax + bilinear sampling -> mid (fp32)
    sample_kernel<<<NQ / QPB, 256, 0, stream>>>(v_f32, oa_f32, refp, mid);
    // out = mid @ W_o + b_o  (fp32 out)
    gemm_bias_kernel<<<dim3(NQ / TM, 256 / TN), 256, 0, stream>>>(
        mid, WtOh, WtOl, b_o, (float*)d_out, NQ, 256, 256);
}

// Round 4
// 225.576 us; speedup vs baseline: 1.4843x; 1.1703x over previous
//
#include <hip/hip_runtime.h>

#define NH 8
#define HD 32
#define SUMP 16
#define LQ 4096
#define BS 4
#define LV 8500
#define NQ (BS * LQ)   // 16384
#define MV (BS * LV)   // 34000

typedef short s16x8 __attribute__((ext_vector_type(8)));
typedef short s16x4 __attribute__((ext_vector_type(4)));
typedef float f32x4 __attribute__((ext_vector_type(4)));
typedef unsigned short ushort_t;

__device__ __forceinline__ float bf2f(unsigned short u) {
    union { unsigned int i; float f; } x; x.i = ((unsigned int)u) << 16; return x.f;
}
__device__ __forceinline__ unsigned short f2bf(float f) {
    union { float f; unsigned int i; } x; x.f = f;
    unsigned int r = x.i + 0x7fffu + ((x.i >> 16) & 1u);
    return (unsigned short)(r >> 16);
}
// split fp32 -> bf16 hi + bf16 lo (a ~= hi + lo, error ~2^-17 |a|)
__device__ __forceinline__ void split8(const float* f, s16x8& hi, s16x8& lo) {
    #pragma unroll
    for (int i = 0; i < 8; ++i) {
        unsigned short h = f2bf(f[i]);
        float r = f[i] - bf2f(h);
        hi[i] = (short)h;
        lo[i] = (short)f2bf(r);
    }
}

// ---------- prep: transpose + split weights into Wt_hi/Wt_lo [N][K], concat biases ----------
__global__ __launch_bounds__(256) void prep_kernel(
    const float* __restrict__ Wv, const float* __restrict__ Woff,
    const float* __restrict__ Wattn, const float* __restrict__ Wo,
    const float* __restrict__ boff, const float* __restrict__ battn,
    unsigned short* __restrict__ WtVh, unsigned short* __restrict__ WtVl,
    unsigned short* __restrict__ WtOAh, unsigned short* __restrict__ WtOAl,
    unsigned short* __restrict__ WtOh, unsigned short* __restrict__ WtOl,
    float* __restrict__ biasOA)
{
    int r = blockIdx.x;      // 0..895
    int k = threadIdx.x;     // 0..255
    float w; unsigned short* ph; unsigned short* pl; size_t idx;
    if (r < 256)      { w = Wv[k * 256 + r];                 ph = WtVh;  pl = WtVl;  idx = (size_t)r * 256 + k; }
    else if (r < 512) { int n = r - 256; w = Woff[k * 256 + n];  ph = WtOAh; pl = WtOAl; idx = (size_t)n * 256 + k; }
    else if (r < 640) { int n = r - 512; w = Wattn[k * 128 + n]; ph = WtOAh; pl = WtOAl; idx = (size_t)(256 + n) * 256 + k; }
    else              { int n = r - 640; w = Wo[k * 256 + n];    ph = WtOh;  pl = WtOl;  idx = (size_t)n * 256 + k; }
    unsigned short h = f2bf(w);
    float res = w - bf2f(h);
    ph[idx] = h;
    pl[idx] = f2bf(res);
    if (r == 0) biasOA[k] = boff[k];
    if (r == 1 && k < 128) biasOA[256 + k] = battn[k];
}

// ---------- split query fp32 -> Qh/Ql bf16 planes ----------
__global__ __launch_bounds__(256) void splitq_kernel(
    const float* __restrict__ q, unsigned short* __restrict__ Qh, unsigned short* __restrict__ Ql)
{
    size_t i = ((size_t)blockIdx.x * 256 + threadIdx.x) * 8;   // NQ*256 elems, 8/thread
    float buf[8];
    *(float4*)(buf + 0) = *(const float4*)(q + i);
    *(float4*)(buf + 4) = *(const float4*)(q + i + 4);
    s16x8 hi, lo;
    split8(buf, hi, lo);
    *(s16x8*)(Qh + i) = hi;
    *(s16x8*)(Ql + i) = lo;
}

// ---------- GEMM body: C[M][256? N] = A[M][256] @ Bt[N][256]^T + bias, K=256 ----------
#define LDT 40   // padded LDS row stride (elements); 80B rows, 16B aligned

template <int NI, bool A_FP32>
__device__ __forceinline__ void gemm_body(
    const float* __restrict__ Af,
    const unsigned short* __restrict__ Ahp, const unsigned short* __restrict__ Alp,
    const unsigned short* __restrict__ Bth, const unsigned short* __restrict__ Btl,
    const float* __restrict__ bias, float* __restrict__ C,
    int M, int N, int mb, int nb,
    unsigned short* Ah, unsigned short* Al, unsigned short* Bh, unsigned short* Bl)
{
    const int t = threadIdx.x;
    const int wave = t >> 6, lane = t & 63;
    const int quad = lane >> 4, l16 = lane & 15;
    const int m0 = mb * 128;
    const int n0 = nb * (NI * 16);

    f32x4 acc[2][NI] = {};

    for (int k0 = 0; k0 < 256; k0 += 32) {
        // stage A tile 128x32
        #pragma unroll
        for (int c = 0; c < 2; ++c) {
            int row = (t >> 2) + c * 64;
            int kq = t & 3;
            int gm = m0 + row;
            if (A_FP32) {
                float buf[8] = {};
                if (gm < M) {
                    *(float4*)(buf + 0) = *(const float4*)(Af + (size_t)gm * 256 + k0 + kq * 8);
                    *(float4*)(buf + 4) = *(const float4*)(Af + (size_t)gm * 256 + k0 + kq * 8 + 4);
                }
                s16x8 hi, lo;
                split8(buf, hi, lo);
                *(s16x8*)(Ah + row * LDT + kq * 8) = hi;
                *(s16x8*)(Al + row * LDT + kq * 8) = lo;
            } else {
                s16x8 hi = {}, lo = {};
                if (gm < M) {
                    size_t g = (size_t)gm * 256 + k0 + kq * 8;
                    hi = *(const s16x8*)(Ahp + g);
                    lo = *(const s16x8*)(Alp + g);
                }
                *(s16x8*)(Ah + row * LDT + kq * 8) = hi;
                *(s16x8*)(Al + row * LDT + kq * 8) = lo;
            }
        }
        // stage B tile (NI*16)x32, pre-split bf16
        #pragma unroll
        for (int c = 0; c < NI / 4; ++c) {
            int row = (t >> 2) + c * 64;
            int kq = t & 3;
            size_t g = (size_t)(n0 + row) * 256 + k0 + kq * 8;
            *(s16x8*)(Bh + row * LDT + kq * 8) = *(const s16x8*)(Bth + g);
            *(s16x8*)(Bl + row * LDT + kq * 8) = *(const s16x8*)(Btl + g);
        }
        __syncthreads();

        s16x8 afh[2], afl[2], bfh[NI], bfl[NI];
        #pragma unroll
        for (int mi = 0; mi < 2; ++mi) {
            int r = (wave * 32 + mi * 16 + l16) * LDT + quad * 8;
            afh[mi] = *(const s16x8*)(Ah + r);
            afl[mi] = *(const s16x8*)(Al + r);
        }
        #pragma unroll
        for (int ni = 0; ni < NI; ++ni) {
            int r = (ni * 16 + l16) * LDT + quad * 8;
            bfh[ni] = *(const s16x8*)(Bh + r);
            bfl[ni] = *(const s16x8*)(Bl + r);
        }
        #pragma unroll
        for (int mi = 0; mi < 2; ++mi) {
            #pragma unroll
            for (int ni = 0; ni < NI; ++ni) {
                acc[mi][ni] = __builtin_amdgcn_mfma_f32_16x16x32_bf16(afh[mi], bfh[ni], acc[mi][ni], 0, 0, 0);
                acc[mi][ni] = __builtin_amdgcn_mfma_f32_16x16x32_bf16(afh[mi], bfl[ni], acc[mi][ni], 0, 0, 0);
                acc[mi][ni] = __builtin_amdgcn_mfma_f32_16x16x32_bf16(afl[mi], bfh[ni], acc[mi][ni], 0, 0, 0);
            }
        }
        __syncthreads();
    }

    // epilogue: C/D layout col=lane&15, row=quad*4+reg
    #pragma unroll
    for (int ni = 0; ni < NI; ++ni) {
        int n = n0 + ni * 16 + l16;
        float bv = bias[n];
        #pragma unroll
        for (int mi = 0; mi < 2; ++mi) {
            int mb2 = m0 + wave * 32 + mi * 16 + quad * 4;
            #pragma unroll
            for (int r = 0; r < 4; ++r) {
                int m = mb2 + r;
                if (m < M) C[(size_t)m * N + n] = acc[mi][ni][r] + bv;
            }
        }
    }
}

// dual-packed: blocks [0, nblk0) = GEMM-V (fp32 A, on-fly split); rest = GEMM-OA (bf16 A)
__global__ __launch_bounds__(256) void gemm_dual_kernel(
    const float* __restrict__ A0, const unsigned short* __restrict__ B0h,
    const unsigned short* __restrict__ B0l, const float* __restrict__ bias0,
    float* __restrict__ C0, int M0, int mblk0, int nblk0,
    const unsigned short* __restrict__ A1h, const unsigned short* __restrict__ A1l,
    const unsigned short* __restrict__ B1h, const unsigned short* __restrict__ B1l,
    const float* __restrict__ bias1, float* __restrict__ C1, int M1, int mblk1)
{
    __shared__ __align__(16) unsigned short Ah[128 * LDT];
    __shared__ __align__(16) unsigned short Al[128 * LDT];
    __shared__ __align__(16) unsigned short Bh[128 * LDT];
    __shared__ __align__(16) unsigned short Bl[128 * LDT];
    int bid = blockIdx.x;
    if (bid < nblk0) {
        int mb = bid % mblk0, nb = bid / mblk0;
        gemm_body<8, true>(A0, nullptr, nullptr, B0h, B0l, bias0, C0, M0, 256, mb, nb,
                           Ah, Al, Bh, Bl);
    } else {
        bid -= nblk0;
        int mb = bid % mblk1, nb = bid / mblk1;
        gemm_body<8, false>(nullptr, A1h, A1l, B1h, B1l, bias1, C1, M1, 384, mb, nb,
                            Ah, Al, Bh, Bl);
    }
}

// final GEMM: out = mid @ W_o + b_o, A pre-split bf16, TN=64 for more blocks
__global__ __launch_bounds__(256) void gemm_o_kernel(
    const unsigned short* __restrict__ Ahp, const unsigned short* __restrict__ Alp,
    const unsigned short* __restrict__ Bth, const unsigned short* __restrict__ Btl,
    const float* __restrict__ bias, float* __restrict__ C, int M)
{
    __shared__ __align__(16) unsigned short Ah[128 * LDT];
    __shared__ __align__(16) unsigned short Al[128 * LDT];
    __shared__ __align__(16) unsigned short Bh[64 * LDT];
    __shared__ __align__(16) unsigned short Bl[64 * LDT];
    gemm_body<4, false>(nullptr, Ahp, Alp, Bth, Btl, bias, C, M, 256,
                        blockIdx.x, blockIdx.y, Ah, Al, Bh, Bl);
}

// ---------- sampling: softmax + precomputed corner weights/indices + gather ----------
#define QPB 4   // queries per block

__global__ __launch_bounds__(256) void sample_kernel(
    const float* __restrict__ v,             // [MV][256] fp32, col = h*32+d
    const float* __restrict__ oa,            // [NQ][384] fp32: 0..255 offsets, 256..383 logits
    const float* __restrict__ refp,          // [NQ][4] fp32
    unsigned short* __restrict__ Mh,         // [NQ][256] bf16 hi
    unsigned short* __restrict__ Ml)         // [NQ][256] bf16 lo
{
    const int row0 = blockIdx.x * QPB;
    const int t = threadIdx.x;

    __shared__ float s_lx[QPB][128];
    __shared__ float s_ly[QPB][128];
    __shared__ float s_raw[QPB][128];
    __shared__ float s_mx[QPB][NH], s_is[QPB][NH];
    __shared__ int4   s_idx[QPB][NH][17];   // [p]: 4 corner byte-offsets; 17 pads h-stride to 68 words (conflict-free)
    __shared__ float4 s_w4[QPB][NH][17];    // [p]: 4 masked corner weights

    // --- P1: locations + raw logits (512 entries, 2/thread) ---
    for (int i = t; i < QPB * 128; i += 256) {
        int q = i >> 7, e = i & 127;          // e = h*16 + p
        int row = row0 + q;
        float4 r4 = *(const float4*)(refp + (size_t)row * 4);
        float2 o2 = *(const float2*)(oa + (size_t)row * 384 + e * 2);
        // loc = ref_xy + off * (1/P) * ref_wh * OFFSET_SCALE = ref_xy + off*0.125*ref_wh
        s_lx[q][e] = r4.x + o2.x * 0.125f * r4.z;
        s_ly[q][e] = r4.y + o2.y * 0.125f * r4.w;
        s_raw[q][e] = oa[(size_t)row * 384 + 256 + e];
    }
    __syncthreads();
    // --- P2: softmax stats, one (q,h) per thread ---
    if (t < QPB * NH) {
        int q = t >> 3, h = t & 7;
        float mx = -1e30f;
        #pragma unroll
        for (int p = 0; p < SUMP; ++p) mx = fmaxf(mx, s_raw[q][h * 16 + p]);
        float sm = 0.f;
        #pragma unroll
        for (int p = 0; p < SUMP; ++p) sm += __expf(s_raw[q][h * 16 + p] - mx);
        s_mx[q][h] = mx; s_is[q][h] = 1.f / sm;
    }
    __syncthreads();
    // --- P3: per (q,h,p) compute 4 masked weights + 4 byte offsets ---
    for (int i = t; i < QPB * 128; i += 256) {
        int q = i >> 7, e = i & 127, h = e >> 4, p = e & 15, l = p >> 2;
        int Wl = 80 >> l;                                    // 80,40,20,10
        int vst = (l == 0) ? 0 : (l == 1) ? 6400 : (l == 2) ? 8000 : 8400;
        float w = __expf(s_raw[q][e] - s_mx[q][h]) * s_is[q][h];
        float x = s_lx[q][e] * Wl - 0.5f;
        float y = s_ly[q][e] * Wl - 0.5f;
        float x0f = floorf(x), y0f = floorf(y);
        float lx = x - x0f, ly = y - y0f;
        int x0 = (int)x0f, y0 = (int)y0f;
        int x1 = x0 + 1, y1 = y0 + 1;
        float mx0 = (x0 >= 0 && x0 < Wl) ? 1.f : 0.f;
        float mx1 = (x1 >= 0 && x1 < Wl) ? 1.f : 0.f;
        float my0 = (y0 >= 0 && y0 < Wl) ? 1.f : 0.f;
        float my1 = (y1 >= 0 && y1 < Wl) ? 1.f : 0.f;
        int cx0 = min(max(x0, 0), Wl - 1), cx1 = min(max(x1, 0), Wl - 1);
        int cy0 = min(max(y0, 0), Wl - 1), cy1 = min(max(y1, 0), Wl - 1);
        int base = (vst * 256 + h * 32) * 4;                 // bytes within batch plane
        int4 id;
        id.x = base + (cy0 * Wl + cx0) * 1024;               // 256 floats * 4B per value row
        id.y = base + (cy0 * Wl + cx1) * 1024;
        id.z = base + (cy1 * Wl + cx0) * 1024;
        id.w = base + (cy1 * Wl + cx1) * 1024;
        s_idx[q][h][p] = id;
        float4 w4;
        w4.x = w * (1.f - lx) * (1.f - ly) * mx0 * my0;
        w4.y = w * lx * (1.f - ly) * mx1 * my0;
        w4.z = w * (1.f - lx) * ly * mx0 * my1;
        w4.w = w * lx * ly * mx1 * my1;
        s_w4[q][h][p] = w4;
    }
    __syncthreads();

    // --- P4: gather. wave = query; h = (t>>3)&7, dv = t&7 (float4 over HD) ---
    const int q = t >> 6;
    const int h = (t >> 3) & 7;
    const int dv = t & 7;
    const int row = row0 + q;
    const int b = row >> 12;                  // LQ = 4096
    const char* vb = (const char*)v + (size_t)b * LV * 1024 + dv * 16;

    f32x4 acc = {};
    #pragma unroll
    for (int p = 0; p < 16; ++p) {
        int4 id = s_idx[q][h][p];
        float4 w4 = s_w4[q][h][p];
        float4 g0 = *(const float4*)(vb + id.x);
        float4 g1 = *(const float4*)(vb + id.y);
        float4 g2 = *(const float4*)(vb + id.z);
        float4 g3 = *(const float4*)(vb + id.w);
        acc[0] += w4.x * g0.x + w4.y * g1.x + w4.z * g2.x + w4.w * g3.x;
        acc[1] += w4.x * g0.y + w4.y * g1.y + w4.z * g2.y + w4.w * g3.y;
        acc[2] += w4.x * g0.z + w4.y * g1.z + w4.z * g2.z + w4.w * g3.z;
        acc[3] += w4.x * g0.w + w4.y * g1.w + w4.z * g2.w + w4.w * g3.w;
    }
    // write mid pre-split to bf16 hi/lo planes
    size_t off = (size_t)row * 256 + h * 32 + dv * 4;
    s16x4 h4, l4;
    #pragma unroll
    for (int c = 0; c < 4; ++c) {
        unsigned short hv = f2bf(acc[c]);
        h4[c] = (short)hv;
        l4[c] = (short)f2bf(acc[c] - bf2f(hv));
    }
    *(s16x4*)(Mh + off) = h4;
    *(s16x4*)(Ml + off) = l4;
}

extern "C" void kernel_launch(void* const* d_in, const int* in_sizes, int n_in,
                              void* d_out, int out_size, void* d_ws, size_t ws_size,
                              hipStream_t stream) {
    const float* query  = (const float*)d_in[0];   // [4,4096,256]
    const float* refp   = (const float*)d_in[1];   // [4,4096,1,4]
    const float* value  = (const float*)d_in[2];   // [4,8500,256]
    const float* W_off  = (const float*)d_in[3];   // [256,256]
    const float* b_off  = (const float*)d_in[4];   // [256]
    const float* W_attn = (const float*)d_in[5];   // [256,128]
    const float* b_attn = (const float*)d_in[6];   // [128]
    const float* W_v    = (const float*)d_in[7];   // [256,256]
    const float* b_v    = (const float*)d_in[8];   // [256]
    const float* W_o    = (const float*)d_in[9];   // [256,256]
    const float* b_o    = (const float*)d_in[10];  // [256]

    char* ws = (char*)d_ws;
    float*          v_f32  = (float*)(ws + 0);                  // 34,816,000 B
    float*          oa_f32 = (float*)(ws + 34816000);           // 25,165,824 B
    unsigned short* Qh     = (unsigned short*)(ws + 59981824);  //  8,388,608 B
    unsigned short* Ql     = (unsigned short*)(ws + 68370432);  //  8,388,608 B
    unsigned short* Mh     = Qh;  // alias: Qh dead after dual-GEMM, Mh written by sample
    unsigned short* Ml     = Ql;
    unsigned short* WtVh   = (unsigned short*)(ws + 76759040);  //    131,072 B
    unsigned short* WtVl   = (unsigned short*)(ws + 76890112);  //    131,072 B
    unsigned short* WtOAh  = (unsigned short*)(ws + 77021184);  //    196,608 B
    unsigned short* WtOAl  = (unsigned short*)(ws + 77217792);  //    196,608 B
    unsigned short* WtOh   = (unsigned short*)(ws + 77414400);  //    131,072 B
    unsigned short* WtOl   = (unsigned short*)(ws + 77545472);  //    131,072 B
    float*          biasOA = (float*)(ws + 77676544);           //      1,536 B

    prep_kernel<<<896, 256, 0, stream>>>(W_v, W_off, W_attn, W_o, b_off, b_attn,
                                         WtVh, WtVl, WtOAh, WtOAl, WtOh, WtOl, biasOA);
    splitq_kernel<<<NQ * 256 / (256 * 8), 256, 0, stream>>>(query, Qh, Ql);
    // dual: v = value@W_v + b_v  AND  oa = query@[W_off|W_attn] + bias
    {
        int mblk0 = (MV + 127) / 128;          // 266
        int nblk0 = mblk0 * 2;                 // 532
        int mblk1 = NQ / 128;                  // 128
        int nblk1 = mblk1 * 3;                 // 384
        gemm_dual_kernel<<<nblk0 + nblk1, 256, 0, stream>>>(
            value, WtVh, WtVl, b_v, v_f32, MV, mblk0, nblk0,
            Qh, Ql, WtOAh, WtOAl, biasOA, oa_f32, NQ, mblk1);
    }
    // softmax + bilinear sampling -> mid (pre-split bf16 hi/lo)
    sample_kernel<<<NQ / QPB, 256, 0, stream>>>(v_f32, oa_f32, refp, Mh, Ml);
    // out = mid @ W_o + b_o  (fp32 out)
    gemm_o_kernel<<<dim3(NQ / 128, 4), 256, 0, stream>>>(
        Mh, Ml, WtOh, WtOl, b_o, (float*)d_out, NQ);
}

// Round 5
// 211.086 us; speedup vs baseline: 1.5862x; 1.0686x over previous
//
#include <hip/hip_runtime.h>

#define NH 8
#define HD 32
#define SUMP 16
#define LQ 4096
#define BS 4
#define LV 8500
#define NQ (BS * LQ)   // 16384
#define MV (BS * LV)   // 34000

typedef short s16x8 __attribute__((ext_vector_type(8)));
typedef short s16x4 __attribute__((ext_vector_type(4)));
typedef float f32x4 __attribute__((ext_vector_type(4)));
typedef _Float16 h16x4 __attribute__((ext_vector_type(4)));
typedef unsigned short ushort_t;

__device__ __forceinline__ float bf2f(unsigned short u) {
    union { unsigned int i; float f; } x; x.i = ((unsigned int)u) << 16; return x.f;
}
__device__ __forceinline__ unsigned short f2bf(float f) {
    union { float f; unsigned int i; } x; x.f = f;
    unsigned int r = x.i + 0x7fffu + ((x.i >> 16) & 1u);
    return (unsigned short)(r >> 16);
}
// split fp32 -> bf16 hi + bf16 lo (a ~= hi + lo, error ~2^-17 |a|)
__device__ __forceinline__ void split8(const float* f, s16x8& hi, s16x8& lo) {
    #pragma unroll
    for (int i = 0; i < 8; ++i) {
        unsigned short h = f2bf(f[i]);
        float r = f[i] - bf2f(h);
        hi[i] = (short)h;
        lo[i] = (short)f2bf(r);
    }
}

// ---------- prep (fused): weight transpose+split, bias concat, query split ----------
__global__ __launch_bounds__(256) void prep_kernel(
    const float* __restrict__ Wv, const float* __restrict__ Woff,
    const float* __restrict__ Wattn, const float* __restrict__ Wo,
    const float* __restrict__ boff, const float* __restrict__ battn,
    const float* __restrict__ query,
    unsigned short* __restrict__ WtVh, unsigned short* __restrict__ WtVl,
    unsigned short* __restrict__ WtOAh, unsigned short* __restrict__ WtOAl,
    unsigned short* __restrict__ WtOh, unsigned short* __restrict__ WtOl,
    float* __restrict__ biasOA,
    unsigned short* __restrict__ Qh, unsigned short* __restrict__ Ql)
{
    int r = blockIdx.x;
    int k = threadIdx.x;     // 0..255
    if (r < 896) {
        float w; unsigned short* ph; unsigned short* pl; size_t idx;
        if (r < 256)      { w = Wv[k * 256 + r];                 ph = WtVh;  pl = WtVl;  idx = (size_t)r * 256 + k; }
        else if (r < 512) { int n = r - 256; w = Woff[k * 256 + n];  ph = WtOAh; pl = WtOAl; idx = (size_t)n * 256 + k; }
        else if (r < 640) { int n = r - 512; w = Wattn[k * 128 + n]; ph = WtOAh; pl = WtOAl; idx = (size_t)(256 + n) * 256 + k; }
        else              { int n = r - 640; w = Wo[k * 256 + n];    ph = WtOh;  pl = WtOl;  idx = (size_t)n * 256 + k; }
        unsigned short h = f2bf(w);
        float res = w - bf2f(h);
        ph[idx] = h;
        pl[idx] = f2bf(res);
        if (r == 0) biasOA[k] = boff[k];
        if (r == 1 && k < 128) biasOA[256 + k] = battn[k];
    } else {
        // split query: blocks 896..2943, 2048 elems/block, 8/thread
        size_t i = ((size_t)(r - 896) * 256 + k) * 8;
        float buf[8];
        *(float4*)(buf + 0) = *(const float4*)(query + i);
        *(float4*)(buf + 4) = *(const float4*)(query + i + 4);
        s16x8 hi, lo;
        split8(buf, hi, lo);
        *(s16x8*)(Qh + i) = hi;
        *(s16x8*)(Ql + i) = lo;
    }
}

// ---------- GEMM body, K=256, conflict-free LDS [kq][row][8], reg-prefetch pipeline ----------
// LDS plane layout: plane[kq][row][0..7] shorts; kq = 32-wide K chunk / 8.
// Staging writes and ds_read_b128 fragment reads are both lane-stride-16B -> bank floor.

template <int NI, bool A_FP32, bool OUT_F16>
__device__ __forceinline__ void gemm_body(
    const float* __restrict__ Af,
    const unsigned short* __restrict__ Ahp, const unsigned short* __restrict__ Alp,
    const unsigned short* __restrict__ Bth, const unsigned short* __restrict__ Btl,
    const float* __restrict__ bias, void* __restrict__ Cv,
    int M, int N, int mb, int nb,
    unsigned short* Ah, unsigned short* Al, unsigned short* Bh, unsigned short* Bl)
{
    const int t = threadIdx.x;
    const int wave = t >> 6, lane = t & 63;
    const int quad = lane >> 4, l16 = lane & 15;
    const int m0 = mb * 128;
    const int n0 = nb * (NI * 16);
    const int arow = t >> 2, kq = t & 3;   // staging coords

    f32x4 acc[2][NI] = {};

    // prefetch registers
    float a_f[2][8];
    s16x8 a_h[2], a_l[2];
    s16x8 b_h[NI / 4], b_l[NI / 4];

#define LOAD_TILE(k0)                                                              \
    {                                                                              \
        _Pragma("unroll")                                                          \
        for (int c = 0; c < 2; ++c) {                                              \
            int gm = m0 + arow + c * 64;                                           \
            if (A_FP32) {                                                          \
                if (gm < M) {                                                      \
                    *(float4*)(a_f[c] + 0) = *(const float4*)(Af + (size_t)gm * 256 + (k0) + kq * 8);     \
                    *(float4*)(a_f[c] + 4) = *(const float4*)(Af + (size_t)gm * 256 + (k0) + kq * 8 + 4); \
                } else {                                                           \
                    _Pragma("unroll") for (int j = 0; j < 8; ++j) a_f[c][j] = 0.f; \
                }                                                                  \
            } else {                                                               \
                if (gm < M) {                                                      \
                    size_t g = (size_t)gm * 256 + (k0) + kq * 8;                   \
                    a_h[c] = *(const s16x8*)(Ahp + g);                             \
                    a_l[c] = *(const s16x8*)(Alp + g);                             \
                } else { a_h[c] = (s16x8){}; a_l[c] = (s16x8){}; }                 \
            }                                                                      \
        }                                                                          \
        _Pragma("unroll")                                                          \
        for (int c = 0; c < NI / 4; ++c) {                                         \
            size_t g = (size_t)(n0 + arow + c * 64) * 256 + (k0) + kq * 8;         \
            b_h[c] = *(const s16x8*)(Bth + g);                                     \
            b_l[c] = *(const s16x8*)(Btl + g);                                     \
        }                                                                          \
    }

    LOAD_TILE(0);

    #pragma unroll
    for (int k = 0; k < 8; ++k) {
        // store prefetched tile to LDS (split A here in fp32 mode)
        #pragma unroll
        for (int c = 0; c < 2; ++c) {
            int row = arow + c * 64;
            s16x8 hi, lo;
            if (A_FP32) { split8(a_f[c], hi, lo); }
            else        { hi = a_h[c]; lo = a_l[c]; }
            *(s16x8*)(Ah + kq * 1024 + row * 8) = hi;
            *(s16x8*)(Al + kq * 1024 + row * 8) = lo;
        }
        #pragma unroll
        for (int c = 0; c < NI / 4; ++c) {
            int row = arow + c * 64;
            *(s16x8*)(Bh + kq * (NI * 128) + row * 8) = b_h[c];
            *(s16x8*)(Bl + kq * (NI * 128) + row * 8) = b_l[c];
        }
        __syncthreads();

        if (k < 7) LOAD_TILE((k + 1) * 32);

        s16x8 afh[2], afl[2], bfh[NI], bfl[NI];
        #pragma unroll
        for (int mi = 0; mi < 2; ++mi) {
            int off = quad * 1024 + (wave * 32 + mi * 16 + l16) * 8;
            afh[mi] = *(const s16x8*)(Ah + off);
            afl[mi] = *(const s16x8*)(Al + off);
        }
        #pragma unroll
        for (int ni = 0; ni < NI; ++ni) {
            int off = quad * (NI * 128) + (ni * 16 + l16) * 8;
            bfh[ni] = *(const s16x8*)(Bh + off);
            bfl[ni] = *(const s16x8*)(Bl + off);
        }
        #pragma unroll
        for (int mi = 0; mi < 2; ++mi) {
            #pragma unroll
            for (int ni = 0; ni < NI; ++ni) {
                acc[mi][ni] = __builtin_amdgcn_mfma_f32_16x16x32_bf16(afh[mi], bfh[ni], acc[mi][ni], 0, 0, 0);
                acc[mi][ni] = __builtin_amdgcn_mfma_f32_16x16x32_bf16(afh[mi], bfl[ni], acc[mi][ni], 0, 0, 0);
                acc[mi][ni] = __builtin_amdgcn_mfma_f32_16x16x32_bf16(afl[mi], bfh[ni], acc[mi][ni], 0, 0, 0);
            }
        }
        __syncthreads();
    }
#undef LOAD_TILE

    // epilogue: C/D layout col=lane&15, row=quad*4+reg
    #pragma unroll
    for (int ni = 0; ni < NI; ++ni) {
        int n = n0 + ni * 16 + l16;
        float bv = bias[n];
        #pragma unroll
        for (int mi = 0; mi < 2; ++mi) {
            int mb2 = m0 + wave * 32 + mi * 16 + quad * 4;
            #pragma unroll
            for (int r = 0; r < 4; ++r) {
                int m = mb2 + r;
                if (m < M) {
                    float o = acc[mi][ni][r] + bv;
                    if (OUT_F16) ((_Float16*)Cv)[(size_t)m * N + n] = (_Float16)o;
                    else         ((float*)Cv)[(size_t)m * N + n] = o;
                }
            }
        }
    }
}

// dual-packed: blocks [0, nblk0) = GEMM-V (fp32 A -> fp16 C); rest = GEMM-OA (bf16 A -> fp32 C)
__global__ __launch_bounds__(256) void gemm_dual_kernel(
    const float* __restrict__ A0, const unsigned short* __restrict__ B0h,
    const unsigned short* __restrict__ B0l, const float* __restrict__ bias0,
    _Float16* __restrict__ C0, int M0, int mblk0, int nblk0,
    const unsigned short* __restrict__ A1h, const unsigned short* __restrict__ A1l,
    const unsigned short* __restrict__ B1h, const unsigned short* __restrict__ B1l,
    const float* __restrict__ bias1, float* __restrict__ C1, int M1, int mblk1)
{
    __shared__ __align__(16) unsigned short Ah[4096];
    __shared__ __align__(16) unsigned short Al[4096];
    __shared__ __align__(16) unsigned short Bh[4096];
    __shared__ __align__(16) unsigned short Bl[4096];
    int bid = blockIdx.x;
    if (bid < nblk0) {
        int mb = bid % mblk0, nb = bid / mblk0;
        gemm_body<8, true, true>(A0, nullptr, nullptr, B0h, B0l, bias0, C0, M0, 256, mb, nb,
                                 Ah, Al, Bh, Bl);
    } else {
        bid -= nblk0;
        int mb = bid % mblk1, nb = bid / mblk1;
        gemm_body<8, false, false>(nullptr, A1h, A1l, B1h, B1l, bias1, C1, M1, 384, mb, nb,
                                   Ah, Al, Bh, Bl);
    }
}

// final GEMM: out = mid @ W_o + b_o, A pre-split bf16, TN=64
__global__ __launch_bounds__(256) void gemm_o_kernel(
    const unsigned short* __restrict__ Ahp, const unsigned short* __restrict__ Alp,
    const unsigned short* __restrict__ Bth, const unsigned short* __restrict__ Btl,
    const float* __restrict__ bias, float* __restrict__ C, int M)
{
    __shared__ __align__(16) unsigned short Ah[4096];
    __shared__ __align__(16) unsigned short Al[4096];
    __shared__ __align__(16) unsigned short Bh[2048];
    __shared__ __align__(16) unsigned short Bl[2048];
    gemm_body<4, false, false>(nullptr, Ahp, Alp, Bth, Btl, bias, C, M, 256,
                               blockIdx.x, blockIdx.y, Ah, Al, Bh, Bl);
}

// ---------- sampling: softmax + precomputed corner weights/indices + fp16 gather ----------
#define QPB 4   // queries per block

__global__ __launch_bounds__(256) void sample_kernel(
    const _Float16* __restrict__ v,          // [MV][256] fp16, col = h*32+d
    const float* __restrict__ oa,            // [NQ][384] fp32: 0..255 offsets, 256..383 logits
    const float* __restrict__ refp,          // [NQ][4] fp32
    unsigned short* __restrict__ Mh,         // [NQ][256] bf16 hi
    unsigned short* __restrict__ Ml)         // [NQ][256] bf16 lo
{
    const int row0 = blockIdx.x * QPB;
    const int t = threadIdx.x;

    __shared__ float s_lx[QPB][128];
    __shared__ float s_ly[QPB][128];
    __shared__ float s_raw[QPB][128];
    __shared__ float s_mx[QPB][NH], s_is[QPB][NH];
    __shared__ int4   s_idx[QPB][NH][17];   // 17 pads h-stride to 68 words (conflict-free)
    __shared__ float4 s_w4[QPB][NH][17];

    // --- P1: locations + raw logits ---
    for (int i = t; i < QPB * 128; i += 256) {
        int q = i >> 7, e = i & 127;          // e = h*16 + p
        int row = row0 + q;
        float4 r4 = *(const float4*)(refp + (size_t)row * 4);
        float2 o2 = *(const float2*)(oa + (size_t)row * 384 + e * 2);
        s_lx[q][e] = r4.x + o2.x * 0.125f * r4.z;
        s_ly[q][e] = r4.y + o2.y * 0.125f * r4.w;
        s_raw[q][e] = oa[(size_t)row * 384 + 256 + e];
    }
    __syncthreads();
    // --- P2: softmax stats ---
    if (t < QPB * NH) {
        int q = t >> 3, h = t & 7;
        float mx = -1e30f;
        #pragma unroll
        for (int p = 0; p < SUMP; ++p) mx = fmaxf(mx, s_raw[q][h * 16 + p]);
        float sm = 0.f;
        #pragma unroll
        for (int p = 0; p < SUMP; ++p) sm += __expf(s_raw[q][h * 16 + p] - mx);
        s_mx[q][h] = mx; s_is[q][h] = 1.f / sm;
    }
    __syncthreads();
    // --- P3: per (q,h,p): 4 masked weights + 4 byte offsets (fp16 strides) ---
    for (int i = t; i < QPB * 128; i += 256) {
        int q = i >> 7, e = i & 127, h = e >> 4, p = e & 15, l = p >> 2;
        int Wl = 80 >> l;                                    // 80,40,20,10
        int vst = (l == 0) ? 0 : (l == 1) ? 6400 : (l == 2) ? 8000 : 8400;
        float w = __expf(s_raw[q][e] - s_mx[q][h]) * s_is[q][h];
        float x = s_lx[q][e] * Wl - 0.5f;
        float y = s_ly[q][e] * Wl - 0.5f;
        float x0f = floorf(x), y0f = floorf(y);
        float lx = x - x0f, ly = y - y0f;
        int x0 = (int)x0f, y0 = (int)y0f;
        int x1 = x0 + 1, y1 = y0 + 1;
        float mx0 = (x0 >= 0 && x0 < Wl) ? 1.f : 0.f;
        float mx1 = (x1 >= 0 && x1 < Wl) ? 1.f : 0.f;
        float my0 = (y0 >= 0 && y0 < Wl) ? 1.f : 0.f;
        float my1 = (y1 >= 0 && y1 < Wl) ? 1.f : 0.f;
        int cx0 = min(max(x0, 0), Wl - 1), cx1 = min(max(x1, 0), Wl - 1);
        int cy0 = min(max(y0, 0), Wl - 1), cy1 = min(max(y1, 0), Wl - 1);
        int base = (vst * 256 + h * 32) * 2;                 // bytes within batch plane (fp16)
        int4 id;
        id.x = base + (cy0 * Wl + cx0) * 512;                // 256 halfs * 2B per value row
        id.y = base + (cy0 * Wl + cx1) * 512;
        id.z = base + (cy1 * Wl + cx0) * 512;
        id.w = base + (cy1 * Wl + cx1) * 512;
        s_idx[q][h][p] = id;
        float4 w4;
        w4.x = w * (1.f - lx) * (1.f - ly) * mx0 * my0;
        w4.y = w * lx * (1.f - ly) * mx1 * my0;
        w4.z = w * (1.f - lx) * ly * mx0 * my1;
        w4.w = w * lx * ly * mx1 * my1;
        s_w4[q][h][p] = w4;
    }
    __syncthreads();

    // --- P4: gather. wave = query; h = (t>>3)&7, dv = t&7 (half4 over HD) ---
    const int q = t >> 6;
    const int h = (t >> 3) & 7;
    const int dv = t & 7;
    const int row = row0 + q;
    const int b = row >> 12;                  // LQ = 4096
    const char* vb = (const char*)v + (size_t)b * LV * 512 + dv * 8;

    f32x4 acc = {};
    #pragma unroll
    for (int p = 0; p < 16; ++p) {
        int4 id = s_idx[q][h][p];
        float4 w4 = s_w4[q][h][p];
        h16x4 g0 = *(const h16x4*)(vb + id.x);
        h16x4 g1 = *(const h16x4*)(vb + id.y);
        h16x4 g2 = *(const h16x4*)(vb + id.z);
        h16x4 g3 = *(const h16x4*)(vb + id.w);
        #pragma unroll
        for (int c = 0; c < 4; ++c)
            acc[c] += w4.x * (float)g0[c] + w4.y * (float)g1[c]
                    + w4.z * (float)g2[c] + w4.w * (float)g3[c];
    }
    // write mid pre-split to bf16 hi/lo planes
    size_t off = (size_t)row * 256 + h * 32 + dv * 4;
    s16x4 h4, l4;
    #pragma unroll
    for (int c = 0; c < 4; ++c) {
        unsigned short hv = f2bf(acc[c]);
        h4[c] = (short)hv;
        l4[c] = (short)f2bf(acc[c] - bf2f(hv));
    }
    *(s16x4*)(Mh + off) = h4;
    *(s16x4*)(Ml + off) = l4;
}

extern "C" void kernel_launch(void* const* d_in, const int* in_sizes, int n_in,
                              void* d_out, int out_size, void* d_ws, size_t ws_size,
                              hipStream_t stream) {
    const float* query  = (const float*)d_in[0];   // [4,4096,256]
    const float* refp   = (const float*)d_in[1];   // [4,4096,1,4]
    const float* value  = (const float*)d_in[2];   // [4,8500,256]
    const float* W_off  = (const float*)d_in[3];   // [256,256]
    const float* b_off  = (const float*)d_in[4];   // [256]
    const float* W_attn = (const float*)d_in[5];   // [256,128]
    const float* b_attn = (const float*)d_in[6];   // [128]
    const float* W_v    = (const float*)d_in[7];   // [256,256]
    const float* b_v    = (const float*)d_in[8];   // [256]
    const float* W_o    = (const float*)d_in[9];   // [256,256]
    const float* b_o    = (const float*)d_in[10];  // [256]

    char* ws = (char*)d_ws;
    _Float16*       v_f16  = (_Float16*)(ws + 0);               // 17,408,000 B
    float*          oa_f32 = (float*)(ws + 17408000);           // 25,165,824 B
    unsigned short* Qh     = (unsigned short*)(ws + 42573824);  //  8,388,608 B
    unsigned short* Ql     = (unsigned short*)(ws + 50962432);  //  8,388,608 B
    unsigned short* Mh     = Qh;  // alias: Qh dead after dual-GEMM
    unsigned short* Ml     = Ql;
    unsigned short* WtVh   = (unsigned short*)(ws + 59351040);  //    131,072 B
    unsigned short* WtVl   = (unsigned short*)(ws + 59482112);  //    131,072 B
    unsigned short* WtOAh  = (unsigned short*)(ws + 59613184);  //    196,608 B
    unsigned short* WtOAl  = (unsigned short*)(ws + 59809792);  //    196,608 B
    unsigned short* WtOh   = (unsigned short*)(ws + 60006400);  //    131,072 B
    unsigned short* WtOl   = (unsigned short*)(ws + 60137472);  //    131,072 B
    float*          biasOA = (float*)(ws + 60268544);           //      1,536 B

    // fused prep: weights (blocks 0..895) + query split (blocks 896..2943)
    prep_kernel<<<2944, 256, 0, stream>>>(W_v, W_off, W_attn, W_o, b_off, b_attn, query,
                                          WtVh, WtVl, WtOAh, WtOAl, WtOh, WtOl, biasOA,
                                          Qh, Ql);
    // dual: v = value@W_v + b_v (fp16 out)  AND  oa = query@[W_off|W_attn] + bias
    {
        int mblk0 = (MV + 127) / 128;          // 266
        int nblk0 = mblk0 * 2;                 // 532
        int mblk1 = NQ / 128;                  // 128
        int nblk1 = mblk1 * 3;                 // 384
        gemm_dual_kernel<<<nblk0 + nblk1, 256, 0, stream>>>(
            value, WtVh, WtVl, b_v, v_f16, MV, mblk0, nblk0,
            Qh, Ql, WtOAh, WtOAl, biasOA, oa_f32, NQ, mblk1);
    }
    // softmax + bilinear sampling -> mid (pre-split bf16 hi/lo)
    sample_kernel<<<NQ / QPB, 256, 0, stream>>>(v_f16, oa_f32, refp, Mh, Ml);
    // out = mid @ W_o + b_o  (fp32 out)
    gemm_o_kernel<<<dim3(NQ / 128, 4), 256, 0, stream>>>(
        Mh, Ml, WtOh, WtOl, b_o, (float*)d_out, NQ);
}